// Round 3
// baseline (31346.799 us; speedup 1.0000x reference)
//
#include <hip/hip_runtime.h>
#include <hip/hip_bf16.h>
#include <math.h>

// LSTM: L=2, T=512, B=64, H=1024. Reference dtype is float32; rounds 1-2
// NaN'd when reading inputs as bf16 (fp32-as-bf16 gives NaN bit patterns).
// This version RUNTIME-DETECTS the element dtype from the data (bit-14
// statistic of low halfwords: uniform mantissa bit for fp32, bf16 exp-MSB
// (p~0.046) for bf16) and gates all input loads / output stores on it.
// Internal h/c state is fp32; matmul is bf16 MFMA with fp32 accumulate.
// d_out = concat(hs [T,B,H], output_hs [L,B,H], output_cs [L,B,H]),
// output_cs == output_hs (reference bug replicated).

#define Hh 1024
#define Bb 64
#define Tt 512
#define BH (Bb*Hh)      // 65536
#define G4 (4*Hh)       // 4096

typedef __bf16 v8bf __attribute__((ext_vector_type(8)));
typedef float  v4f  __attribute__((ext_vector_type(4)));
typedef int    v4i  __attribute__((ext_vector_type(4)));
typedef __hip_bfloat16 bf16;

__device__ __forceinline__ float bf2f(bf16 v){ return __bfloat162float(v); }
__device__ __forceinline__ bf16  f2bf(float v){ return __float2bfloat16(v); }

__device__ __forceinline__ v8bf frag_load(const bf16* p) {
    return __builtin_bit_cast(v8bf, *(const v4i*)p);
}
__device__ __forceinline__ v8bf frag_load(const float* p) {
    v4f lo = *(const v4f*)p;
    v4f hi = *(const v4f*)(p + 4);
    v8bf r;
    #pragma unroll
    for (int i = 0; i < 4; ++i) {
        r[i]   = __builtin_bit_cast(__bf16, f2bf(lo[i]));
        r[i+4] = __builtin_bit_cast(__bf16, f2bf(hi[i]));
    }
    return r;
}

template<typename TA, typename TB>
__device__ __forceinline__ v4f kloop(const TA* __restrict__ a, const TB* __restrict__ b) {
    v4f acc = {0.f, 0.f, 0.f, 0.f};
    #pragma unroll
    for (int kk = 0; kk < 32; ++kk)
        acc = __builtin_amdgcn_mfma_f32_16x16x32_bf16(frag_load(a + kk*32),
                                                      frag_load(b + kk*32),
                                                      acc, 0, 0, 0);
    return acc;
}

// flag=1 if underlying elements are fp32, 0 if bf16.
__global__ void detect_dtype(const unsigned int* __restrict__ xw, int* __restrict__ flag) {
    __shared__ int cnt;
    if (threadIdx.x == 0) cnt = 0;
    __syncthreads();
    unsigned int w = xw[threadIdx.x];          // first 1 KB of x — in-bounds either way
    atomicAdd(&cnt, (int)((w >> 14) & 1u));    // bit14 of LOW halfword
    __syncthreads();
    if (threadIdx.x == 0) *flag = (cnt >= 64) ? 1 : 0;   // fp32 ~128, bf16 ~12
}

// hbufs: [layer][parity][BH] f32 ; cstate: [layer][BH] f32
__global__ void init_state(const void* __restrict__ h0, const void* __restrict__ c0,
                           float* __restrict__ hbufs, float* __restrict__ cstate,
                           const int* __restrict__ flag) {
    int i = blockIdx.x * blockDim.x + threadIdx.x;   // covers 2*BH
    if (i >= 2*BH) return;
    int f32 = *flag;
    float h = f32 ? ((const float*)h0)[i] : bf2f(((const bf16*)h0)[i]);
    float c = f32 ? ((const float*)c0)[i] : bf2f(((const bf16*)c0)[i]);
    int l = i >> 16;            // BH = 2^16
    int r = i & (BH-1);
    hbufs[(l*2 + 0)*BH + r] = h;   // t=0 reads parity 0
    cstate[i] = c;
}

// Pipeline step p: layer0 computes t=p, layer1 computes t=p-1.
// Grid 256 = 2 layers x 128 j-slices (8 h-cols). Block 1024 = 16 waves.
// Wave w: ks=w>>3 (0: x/Wi-half, 1: h/Wh-half), rt=(w>>1)&3 (batch tile),
// ct=w&1 (16-col tile). K=1024/half, 32 mfma iters.
__global__ __launch_bounds__(1024)
void lstm_step(const void* __restrict__ xv,
               const void* __restrict__ wiv, const void* __restrict__ biv,
               const void* __restrict__ whv, const void* __restrict__ bhv,
               float* __restrict__ h1dbuf, float* __restrict__ hbufs,
               float* __restrict__ cstate, void* __restrict__ outv,
               const int* __restrict__ flagp, int p)
{
    const int layer  = blockIdx.x >> 7;     // 0..1
    const int jslice = blockIdx.x & 127;    // 0..127
    const int t = p - layer;
    if (t < 0 || t >= Tt) return;           // block-uniform early exit

    const int f32 = __builtin_amdgcn_readfirstlane(*flagp);
    const int jbase = jslice * 8;

    const int tid  = threadIdx.x;
    const int lane = tid & 63;
    const int w    = tid >> 6;              // 0..15
    const int ks   = w >> 3;
    const int rt   = (w >> 1) & 3;
    const int ct   = w & 1;
    const int quad = lane >> 4;
    const int n    = ct*16 + (lane & 15);   // 0..31; gate=n>>3, col=n&7
    const int gcol = (n >> 3)*Hh + jbase + (n & 7);

    const int arow = rt*16 + (lane & 15);
    const size_t aoff  = (size_t)arow * Hh + quad*8;
    const size_t boff  = (size_t)gcol * Hh + quad*8;
    const size_t wbase = (size_t)layer * G4 * Hh;

    const float* hprev = hbufs + (size_t)(layer*2 + (t & 1)) * BH;

    v4f acc;
    if (f32) {
        const float* A = (ks == 0)
            ? ((layer == 0) ? ((const float*)xv + (size_t)t*BH)
                            : (h1dbuf + (size_t)(t & 1)*BH))
            : hprev;
        const float* Bw = (const float*)((ks == 0) ? wiv : whv) + wbase + boff;
        acc = kloop(A + aoff, Bw);
    } else {
        const bf16* Bw = (const bf16*)((ks == 0) ? wiv : whv) + wbase + boff;
        if (ks == 0 && layer == 0) {
            acc = kloop((const bf16*)xv + (size_t)t*BH + aoff, Bw);
        } else {
            const float* A = (ks == 0) ? (h1dbuf + (size_t)(t & 1)*BH) : hprev;
            acc = kloop(A + aoff, Bw);
        }
    }

    __shared__ float part[2][64][32];       // 16 KB
    // C/D layout: col = lane&15, row = quad*4 + reg
    #pragma unroll
    for (int r = 0; r < 4; ++r)
        part[ks][rt*16 + quad*4 + r][n] = acc[r];

    __syncthreads();

    if (tid < 512) {
        const int b  = tid >> 3;
        const int j2 = tid & 7;
        const int j  = jbase + j2;
        float g[4];
        #pragma unroll
        for (int gi = 0; gi < 4; ++gi) {
            int c = gi*8 + j2;
            int boffb = layer*G4 + gi*Hh + j;
            float bias = f32
                ? (((const float*)biv)[boffb] + ((const float*)bhv)[boffb])
                : (bf2f(((const bf16*)biv)[boffb]) + bf2f(((const bf16*)bhv)[boffb]));
            g[gi] = part[0][b][c] + part[1][b][c] + bias;
        }
        float ig = 1.f / (1.f + expf(-g[0]));
        float fg = 1.f / (1.f + expf(-g[1]));
        float gv = tanhf(g[2]);
        float og = 1.f / (1.f + expf(-g[3]));
        const int idx = b*Hh + j;
        float* cst = cstate + (size_t)layer * BH;
        float c_new = cst[idx]*fg + ig*gv;
        float h_new = og * tanhf(c_new);
        cst[idx] = c_new;
        hbufs[(size_t)(layer*2 + ((t+1) & 1)) * BH + idx] = h_new;   // next-step h (fp32)
        if (layer == 0) {
            h1dbuf[(size_t)(t & 1) * BH + idx] = h_new;              // feeds layer1 next launch
        } else {
            if (f32) ((float*)outv)[(size_t)t*BH + idx] = h_new;
            else     ((bf16*)outv)[(size_t)t*BH + idx] = f2bf(h_new);
        }
        if (t == Tt-1) {   // final h per layer -> output_hs and output_cs (ref bug: equal)
            size_t o1 = (size_t)Tt*BH + (size_t)layer*BH + idx;
            size_t o2 = (size_t)Tt*BH + (size_t)(2 + layer)*BH + idx;
            if (f32) { ((float*)outv)[o1] = h_new; ((float*)outv)[o2] = h_new; }
            else     { bf16 hb = f2bf(h_new); ((bf16*)outv)[o1] = hb; ((bf16*)outv)[o2] = hb; }
        }
    }
}

extern "C" void kernel_launch(void* const* d_in, const int* in_sizes, int n_in,
                              void* d_out, int out_size, void* d_ws, size_t ws_size,
                              hipStream_t stream) {
    const void* x  = d_in[0];
    const void* h0 = d_in[1];
    const void* c0 = d_in[2];
    const void* wi = d_in[3];
    const void* bi = d_in[4];
    const void* wh = d_in[5];
    const void* bh = d_in[6];

    // ws layout (~2 MB): flag (256 B) | h1dbuf 2*BH f32 | hbufs 4*BH f32 | cstate 2*BH f32
    char* ws = (char*)d_ws;
    int*   flag   = (int*)ws;
    float* h1dbuf = (float*)(ws + 256);
    float* hbufs  = (float*)(ws + 256 + (size_t)2*BH*4);
    float* cstate = (float*)(ws + 256 + (size_t)6*BH*4);

    detect_dtype<<<1, 256, 0, stream>>>((const unsigned int*)x, flag);
    init_state<<<(2*BH + 255)/256, 256, 0, stream>>>(h0, c0, hbufs, cstate, flag);

    for (int p = 0; p <= Tt; ++p) {
        lstm_step<<<256, 1024, 0, stream>>>(x, wi, bi, wh, bh,
                                            h1dbuf, hbufs, cstate, d_out, flag, p);
    }
}

// Round 4
// 18998.807 us; speedup vs baseline: 1.6499x; 1.6499x over previous
//
#include <hip/hip_runtime.h>
#include <hip/hip_bf16.h>
#include <math.h>

// LSTM L=2, T=512, B=64, H=1024 — fp32 in/out (confirmed round 3).
// Persistent-style kernel: weights held bf16 in REGISTERS (128 VGPR/wave),
// 256 blocks x 1024 thr (1 block/CU), manual device-scope grid barrier per
// pipeline step. Layer0 computes t=p while layer1 computes t=p-1.
// d_out = concat(hs [T,B,H], output_hs [L,B,H], output_cs [L,B,H]) fp32,
// output_cs == output_hs (reference bug replicated). c state lives in
// registers and is never written out.

#define Hh 1024
#define Bb 64
#define Tt 512
#define BH (Bb*Hh)      // 65536
#define G4 (4*Hh)       // 4096

typedef __bf16 v8bf __attribute__((ext_vector_type(8)));
typedef float  v4f  __attribute__((ext_vector_type(4)));
typedef int    v4i  __attribute__((ext_vector_type(4)));
typedef __hip_bfloat16 bf16;

__device__ __forceinline__ bf16 f2bf(float v){ return __float2bfloat16(v); }

__device__ __forceinline__ v8bf cvt8(const float* p) {
    v4f a = *(const v4f*)p;
    v4f b = *(const v4f*)(p + 4);
    v8bf r;
    #pragma unroll
    for (int i = 0; i < 4; ++i) {
        r[i]   = __builtin_bit_cast(__bf16, f2bf(a[i]));
        r[i+4] = __builtin_bit_cast(__bf16, f2bf(b[i]));
    }
    return r;
}
__device__ __forceinline__ v8bf ld8bf(const bf16* p) {
    return __builtin_bit_cast(v8bf, *(const v4i*)p);
}
__device__ __forceinline__ float fast_sigmoid(float x) {
    x = fminf(fmaxf(x, -30.f), 30.f);
    return 1.f / (1.f + __expf(-x));
}
__device__ __forceinline__ float fast_tanh(float x) {
    x = fminf(fmaxf(x, -15.f), 15.f);
    float e = __expf(2.f * x);
    return (e - 1.f) / (e + 1.f);
}

// ws: bar (256 B) | xbf[2][BH] bf16 | hout[2 layers][2 parity][BH] bf16
__global__ void init_ws(const float* __restrict__ x, const float* __restrict__ h0,
                        bf16* __restrict__ xbf, bf16* __restrict__ hout,
                        unsigned int* __restrict__ bar) {
    int i = blockIdx.x * blockDim.x + threadIdx.x;   // 256x256 = BH exactly
    if (i == 0) *bar = 0u;
    xbf[i] = f2bf(x[i]);                      // x[t=0] -> slot 0
    hout[(0*2 + 1)*BH + i] = f2bf(h0[i]);     // layer0 reads parity (p-1)&1=1 at p=0
    hout[(1*2 + 0)*BH + i] = f2bf(h0[BH + i]);// layer1 reads parity 0 at p=1
}

// Block b: layer = b>>7, jslice = b&127 (8 j-cols, 32 gate-cols).
// 16 waves = ks(2: Wi/x vs Wh/h) x kh(2: K-half of 512) x rt(4: 16-row tile).
// Each wave holds B-fragments for its (ks,kh) slice x all 32 cols in regs.
__global__ __launch_bounds__(1024, 4)
void lstm_persist(const float* __restrict__ x,
                  const float* __restrict__ wi, const float* __restrict__ bi,
                  const float* __restrict__ wh, const float* __restrict__ bh,
                  const float* __restrict__ c0,
                  bf16* __restrict__ xbf, bf16* __restrict__ hout,
                  float* __restrict__ out, unsigned int* __restrict__ bar)
{
    const int layer  = blockIdx.x >> 7;
    const int jslice = blockIdx.x & 127;
    const int jbase  = jslice * 8;

    const int tid  = threadIdx.x;
    const int lane = tid & 63;
    const int w    = tid >> 6;          // 0..15
    const int ks   = w >> 3;            // 0: x-half(Wi), 1: h-half(Wh)
    const int kh   = (w >> 2) & 1;      // K half (512 each)
    const int rt   = w & 3;             // row tile
    const int s    = w >> 2;            // partial index 0..3
    const int quad = lane >> 4;
    const int l15  = lane & 15;

    // ---- load weights into registers (bf16 fragments) ----
    const float* W = (ks ? wh : wi) + (size_t)layer * G4 * Hh;
    v8bf Breg[16][2];
    #pragma unroll
    for (int ct = 0; ct < 2; ++ct) {
        const int n    = ct*16 + l15;
        const int grow = (n >> 3)*Hh + jbase + (n & 7);
        const float* wp = W + (size_t)grow * Hh + kh*512 + quad*8;
        #pragma unroll
        for (int kk = 0; kk < 16; ++kk)
            Breg[kk][ct] = cvt8(wp + kk*32);
    }

    // A-fragment offset within the chosen activation buffer
    const int arow = rt*16 + l15;
    const size_t aoff = (size_t)arow * Hh + kh*512 + quad*8;

    // ---- epilogue per-thread constants (tid < 512) ----
    const int eb = tid >> 3;            // batch row 0..63
    const int ej = tid & 7;             // j within slice
    float bsum[4];
    float c_reg = 0.f;
    if (tid < 512) {
        #pragma unroll
        for (int gi = 0; gi < 4; ++gi) {
            int bo = layer*G4 + gi*Hh + jbase + ej;
            bsum[gi] = bi[bo] + bh[bo];
        }
        c_reg = c0[(size_t)layer*BH + eb*Hh + jbase + ej];
    }

    __shared__ float part[4][64][36];   // padded: write & read <=2-way conflicts

    for (int p = 0; p <= Tt; ++p) {
        const int t = p - layer;
        const bool act = (t >= 0) & (t < Tt);

        if (act) {
            const bf16* A;
            if (ks == 0)
                A = (layer == 0) ? (xbf + (size_t)(t & 1)*BH)
                                 : (hout + (size_t)((p-1) & 1)*BH);       // hout[0][(p-1)&1]
            else
                A = hout + (size_t)(layer*2 + ((p-1) & 1))*BH;            // own prev h
            const bf16* ap = A + aoff;

            v4f acc0 = {0.f,0.f,0.f,0.f}, acc1 = {0.f,0.f,0.f,0.f};
            #pragma unroll
            for (int kk = 0; kk < 16; ++kk) {
                v8bf af = ld8bf(ap + kk*32);
                acc0 = __builtin_amdgcn_mfma_f32_16x16x32_bf16(af, Breg[kk][0], acc0, 0,0,0);
                acc1 = __builtin_amdgcn_mfma_f32_16x16x32_bf16(af, Breg[kk][1], acc1, 0,0,0);
            }
            // C/D layout: col = lane&15, row = quad*4 + r
            #pragma unroll
            for (int r = 0; r < 4; ++r) {
                part[s][rt*16 + quad*4 + r][l15]      = acc0[r];
                part[s][rt*16 + quad*4 + r][16 + l15] = acc1[r];
            }
        }
        __syncthreads();

        if (tid < 512) {
            if (act) {
                float g[4];
                #pragma unroll
                for (int gi = 0; gi < 4; ++gi) {
                    int c = gi*8 + ej;
                    g[gi] = part[0][eb][c] + part[1][eb][c]
                          + part[2][eb][c] + part[3][eb][c] + bsum[gi];
                }
                float ig = fast_sigmoid(g[0]);
                float fg = fast_sigmoid(g[1]);
                float gv = fast_tanh(g[2]);
                float og = fast_sigmoid(g[3]);
                c_reg = c_reg*fg + ig*gv;
                float h_new = og * fast_tanh(c_reg);

                const int idx = eb*Hh + jbase + ej;
                hout[(size_t)(layer*2 + (p & 1))*BH + idx] = f2bf(h_new);
                if (layer == 1)
                    out[(size_t)t*BH + idx] = h_new;
                if (t == Tt-1) {
                    out[(size_t)Tt*BH + (size_t)layer*BH + idx]       = h_new;
                    out[(size_t)Tt*BH + (size_t)(2 + layer)*BH + idx] = h_new;
                }
            }
        } else if (tid < 768) {
            if (p <= 510) {   // convert x_{p+1} -> slot (p+1)&1 (read after barrier)
                int xi = blockIdx.x*256 + (tid - 512);
                xbf[(size_t)((p+1) & 1)*BH + xi] = f2bf(x[(size_t)(p+1)*BH + xi]);
            }
        }

        if (p < Tt) {   // grid barrier (skip after final step)
            __syncthreads();                     // drains vmem before s_barrier
            if (tid == 0) {
                __threadfence();                 // release: wb L2 (covers block's stores)
                atomicAdd(bar, 1u);
                const unsigned int target = (unsigned int)(p + 1) * 256u;
                while (__hip_atomic_load(bar, __ATOMIC_RELAXED, __HIP_MEMORY_SCOPE_AGENT) < target)
                    __builtin_amdgcn_s_sleep(2);
                __threadfence();                 // acquire: inv stale L1/L2
            }
            __syncthreads();
        }
    }
}

extern "C" void kernel_launch(void* const* d_in, const int* in_sizes, int n_in,
                              void* d_out, int out_size, void* d_ws, size_t ws_size,
                              hipStream_t stream) {
    const float* x  = (const float*)d_in[0];
    const float* h0 = (const float*)d_in[1];
    const float* c0 = (const float*)d_in[2];
    const float* wi = (const float*)d_in[3];
    const float* bi = (const float*)d_in[4];
    const float* wh = (const float*)d_in[5];
    const float* bh = (const float*)d_in[6];
    float* out = (float*)d_out;

    // ws: bar 256 B | xbf 2*BH bf16 (256 KB) | hout 4*BH bf16 (512 KB)
    char* ws = (char*)d_ws;
    unsigned int* bar = (unsigned int*)ws;
    bf16* xbf  = (bf16*)(ws + 256);
    bf16* hout = (bf16*)(ws + 256 + (size_t)2*BH*2);

    init_ws<<<256, 256, 0, stream>>>(x, h0, xbf, hout, bar);
    lstm_persist<<<256, 1024, 0, stream>>>(x, wi, bi, wh, bh, c0,
                                           xbf, hout, out, bar);
}